// Round 1
// baseline (407.852 us; speedup 1.0000x reference)
//
#include <hip/hip_runtime.h>
#include <math.h>

#define N_NODES 50000
#define N_EDGES 800000
#define NFEAT 256
#define NHID 32
#define NHEADS 4
#define ALPHA 0.2f

__device__ __forceinline__ float elu_f(float x) {
    return x > 0.0f ? x : (__expf(x) - 1.0f);
}

// ---------- W1 transform: Ws[4][256][32] -> W1[256][128] (col = head*32+j) ----------
__global__ void k_w1(const float* __restrict__ Ws, float* __restrict__ W1) {
    int idx = blockIdx.x * 256 + threadIdx.x;
    if (idx >= 256 * 128) return;
    int k = idx >> 7;
    int c = idx & 127;
    int h = c >> 5;
    int j = c & 31;
    W1[idx] = Ws[h * (NFEAT * NHID) + k * NHID + j];
}

// ---------- generic tiled f32 GEMM: C[nrows,NC] = A[nrows,K] @ B[K,NC] ----------
template <int K, int NC>
__global__ __launch_bounds__(256) void k_gemm(const float* __restrict__ A,
                                              const float* __restrict__ B,
                                              float* __restrict__ C, int nrows) {
    const int BM = 64, BK = 16, TN = 4;
    const int TCOLS = NC / TN;       // 32 (NC=128) or 8 (NC=32)
    const int TROWS = 256 / TCOLS;   // 8 or 32
    const int TM = BM / TROWS;       // 8 or 2

    __shared__ float As_s[BM * (BK + 1)];
    __shared__ float Bs_s[BK * NC];

    int tid = threadIdx.x;
    int tc = tid % TCOLS;
    int tr = tid / TCOLS;
    int row0 = blockIdx.x * BM;

    float acc[TM][TN];
#pragma unroll
    for (int i = 0; i < TM; i++)
#pragma unroll
        for (int j = 0; j < TN; j++) acc[i][j] = 0.0f;

    for (int k0 = 0; k0 < K; k0 += BK) {
        // stage A tile (64x16), 4 consecutive k per thread, float4 loads
        {
            int idx = tid * 4;
            int r = idx >> 4;
            int kk = idx & 15;
            int gr = row0 + r;
            if (gr >= nrows) gr = nrows - 1;
            const float4 v = *(const float4*)(A + (size_t)gr * K + k0 + kk);
            float* d = &As_s[r * (BK + 1) + kk];
            d[0] = v.x; d[1] = v.y; d[2] = v.z; d[3] = v.w;
        }
        // stage B tile (16xNC)
        {
            const int PER = BK * NC / 256;
#pragma unroll
            for (int p = 0; p < PER; p++) {
                int idx = tid + p * 256;
                int kk = idx / NC;
                int c = idx % NC;
                Bs_s[idx] = B[(size_t)(k0 + kk) * NC + c];
            }
        }
        __syncthreads();
#pragma unroll
        for (int kk = 0; kk < BK; kk++) {
            float4 bv = *(const float4*)&Bs_s[kk * NC + tc * TN];
#pragma unroll
            for (int i = 0; i < TM; i++) {
                float av = As_s[(tr + i * TROWS) * (BK + 1) + kk];
                acc[i][0] += av * bv.x;
                acc[i][1] += av * bv.y;
                acc[i][2] += av * bv.z;
                acc[i][3] += av * bv.w;
            }
        }
        __syncthreads();
    }
#pragma unroll
    for (int i = 0; i < TM; i++) {
        int gr = row0 + tr + i * TROWS;
        if (gr < nrows) {
            float4 v = make_float4(acc[i][0], acc[i][1], acc[i][2], acc[i][3]);
            *(float4*)(C + (size_t)gr * NC + tc * TN) = v;
        }
    }
}

// ---------- per-node attention scalars, layer 1: s[n][h] = H1[n][h*32..] . As[h][..] ----------
__global__ void k_s1(const float* __restrict__ H1, const float* __restrict__ As,
                     float* __restrict__ S1o, float* __restrict__ S1i) {
    int t = blockIdx.x * 256 + threadIdx.x;
    if (t >= N_NODES * NHEADS) return;
    int n = t >> 2;
    int h = t & 3;
    const float* hp = H1 + (size_t)n * 128 + h * 32;
    const float* ap = As + h * 64;
    float so = 0.0f, si = 0.0f;
#pragma unroll
    for (int k = 0; k < 32; k++) {
        float v = hp[k];
        so += v * ap[k];
        si += v * ap[32 + k];
    }
    S1o[t] = so;
    S1i[t] = si;
}

// ---------- layer 2 scalars ----------
__global__ void k_s2(const float* __restrict__ H2, const float* __restrict__ Ao,
                     float* __restrict__ S2o, float* __restrict__ S2i) {
    int n = blockIdx.x * 256 + threadIdx.x;
    if (n >= N_NODES) return;
    const float* hp = H2 + (size_t)n * 32;
    float so = 0.0f, si = 0.0f;
#pragma unroll
    for (int k = 0; k < 32; k++) {
        float v = hp[k];
        so += v * Ao[k];
        si += v * Ao[32 + k];
    }
    S2o[n] = so;
    S2i[n] = si;
}

// ---------- CSR build ----------
__global__ void k_count(const int* __restrict__ src, int* __restrict__ deg) {
    int e = blockIdx.x * 256 + threadIdx.x;
    if (e >= N_EDGES) return;
    atomicAdd(&deg[src[e]], 1);
}

__global__ void k_blocksum(const int* __restrict__ deg, int* __restrict__ bsum) {
    int i = blockIdx.x * 256 + threadIdx.x;
    int v = (i < N_NODES) ? deg[i] : 0;
#pragma unroll
    for (int off = 32; off; off >>= 1) v += __shfl_down(v, off);
    __shared__ int ls[4];
    if ((threadIdx.x & 63) == 0) ls[threadIdx.x >> 6] = v;
    __syncthreads();
    if (threadIdx.x == 0) bsum[blockIdx.x] = ls[0] + ls[1] + ls[2] + ls[3];
}

__global__ void k_scan_bsum(const int* __restrict__ bsum, int* __restrict__ boff, int nb) {
    __shared__ int s[256];
    int t = threadIdx.x;
    int v = (t < nb) ? bsum[t] : 0;
    s[t] = v;
    __syncthreads();
    for (int off = 1; off < 256; off <<= 1) {
        int add = (t >= off) ? s[t - off] : 0;
        __syncthreads();
        s[t] += add;
        __syncthreads();
    }
    if (t < nb) boff[t] = s[t] - v;  // exclusive
}

__global__ void k_scan_chunks(const int* __restrict__ deg, const int* __restrict__ boff,
                              int* __restrict__ row_ptr, int* __restrict__ cursor) {
    int b = blockIdx.x;
    int t = threadIdx.x;
    int i = b * 256 + t;
    int v = (i < N_NODES) ? deg[i] : 0;
    __shared__ int s[256];
    s[t] = v;
    __syncthreads();
    for (int off = 1; off < 256; off <<= 1) {
        int add = (t >= off) ? s[t - off] : 0;
        __syncthreads();
        s[t] += add;
        __syncthreads();
    }
    int excl = s[t] - v + boff[b];
    if (i < N_NODES) {
        row_ptr[i] = excl;
        cursor[i] = excl;
    }
    if (i == 0) row_ptr[N_NODES] = N_EDGES;
}

__global__ void k_fill(const int* __restrict__ src, const int* __restrict__ dst,
                       int* __restrict__ cursor, int* __restrict__ col) {
    int e = blockIdx.x * 256 + threadIdx.x;
    if (e >= N_EDGES) return;
    int pos = atomicAdd(&cursor[src[e]], 1);
    col[pos] = dst[e];
}

// ---------- layer-1 aggregation: one wave per node, 4 heads, online softmax ----------
__global__ __launch_bounds__(256) void k_agg4(const int* __restrict__ row_ptr,
                                              const int* __restrict__ col,
                                              const float* __restrict__ S1o,
                                              const float* __restrict__ S1i,
                                              const float* __restrict__ H1,
                                              float* __restrict__ Hc) {
    int node = blockIdx.x * 4 + (threadIdx.x >> 6);
    if (node >= N_NODES) return;
    int lane = threadIdx.x & 63;
    int ha = lane >> 5;      // head 0/1 for column `lane`
    int hb = ha + 2;         // head 2/3 for column `lane+64`
    int beg = row_ptr[node];
    int end = row_ptr[node + 1];
    float so_a = S1o[node * 4 + ha];
    float so_b = S1o[node * 4 + hb];
    float m_a = -INFINITY, m_b = -INFINITY;
    float d_a = 0.0f, d_b = 0.0f, acc_a = 0.0f, acc_b = 0.0f;
    for (int i = beg; i < end; i++) {
        int v = col[i];
        float e_a = so_a + S1i[v * 4 + ha];
        float e_b = so_b + S1i[v * 4 + hb];
        e_a = e_a > 0.0f ? e_a : ALPHA * e_a;
        e_b = e_b > 0.0f ? e_b : ALPHA * e_b;
        float hv_a = H1[(size_t)v * 128 + lane];
        float hv_b = H1[(size_t)v * 128 + 64 + lane];
        // online softmax, head a
        float mn = fmaxf(m_a, e_a);
        float sc = __expf(m_a - mn);
        float w = __expf(e_a - mn);
        d_a = d_a * sc + w;
        acc_a = acc_a * sc + w * hv_a;
        m_a = mn;
        // head b
        mn = fmaxf(m_b, e_b);
        sc = __expf(m_b - mn);
        w = __expf(e_b - mn);
        d_b = d_b * sc + w;
        acc_b = acc_b * sc + w * hv_b;
        m_b = mn;
    }
    float oa = d_a > 0.0f ? acc_a / d_a : 0.0f;
    float ob = d_b > 0.0f ? acc_b / d_b : 0.0f;
    Hc[(size_t)node * 128 + lane] = elu_f(oa);
    Hc[(size_t)node * 128 + 64 + lane] = elu_f(ob);
}

// ---------- layer-2 aggregation: half-wave per node, 1 head, 32 feats ----------
__global__ __launch_bounds__(256) void k_agg1(const int* __restrict__ row_ptr,
                                              const int* __restrict__ col,
                                              const float* __restrict__ S2o,
                                              const float* __restrict__ S2i,
                                              const float* __restrict__ H2,
                                              float* __restrict__ out) {
    int t = blockIdx.x * 256 + threadIdx.x;
    int node = t >> 5;
    if (node >= N_NODES) return;
    int l = t & 31;
    int beg = row_ptr[node];
    int end = row_ptr[node + 1];
    float so = S2o[node];
    float m = -INFINITY, d = 0.0f, acc = 0.0f;
    for (int i = beg; i < end; i++) {
        int v = col[i];
        float e = so + S2i[v];
        e = e > 0.0f ? e : ALPHA * e;
        float hv = H2[(size_t)v * 32 + l];
        float mn = fmaxf(m, e);
        float sc = __expf(m - mn);
        float w = __expf(e - mn);
        d = d * sc + w;
        acc = acc * sc + w * hv;
        m = mn;
    }
    float o = d > 0.0f ? acc / d : 0.0f;
    out[(size_t)node * 32 + l] = elu_f(o);
}

extern "C" void kernel_launch(void* const* d_in, const int* in_sizes, int n_in,
                              void* d_out, int out_size, void* d_ws, size_t ws_size,
                              hipStream_t stream) {
    const float* x = (const float*)d_in[0];
    const int* src = (const int*)d_in[1];
    const int* dst = (const int*)d_in[2];
    const float* Ws = (const float*)d_in[3];
    const float* As = (const float*)d_in[4];
    const float* Wo = (const float*)d_in[5];
    const float* Ao = (const float*)d_in[6];
    float* out = (float*)d_out;

    // carve workspace
    char* p = (char*)d_ws;
    auto alloc = [&](size_t bytes) -> void* {
        void* r = (void*)p;
        p += (bytes + 255) & ~(size_t)255;
        return r;
    };
    float* W1  = (float*)alloc((size_t)256 * 128 * 4);
    float* H1  = (float*)alloc((size_t)N_NODES * 128 * 4);
    float* S1o = (float*)alloc((size_t)N_NODES * 4 * 4);
    float* S1i = (float*)alloc((size_t)N_NODES * 4 * 4);
    float* Hc  = (float*)alloc((size_t)N_NODES * 128 * 4);
    float* H2  = (float*)alloc((size_t)N_NODES * 32 * 4);
    float* S2o = (float*)alloc((size_t)N_NODES * 4);
    float* S2i = (float*)alloc((size_t)N_NODES * 4);
    int* deg     = (int*)alloc((size_t)N_NODES * 4);
    int* row_ptr = (int*)alloc((size_t)(N_NODES + 1) * 4);
    int* cursor  = (int*)alloc((size_t)N_NODES * 4);
    int* col     = (int*)alloc((size_t)N_EDGES * 4);
    int* bsum    = (int*)alloc(256 * 4);
    int* boff    = (int*)alloc(256 * 4);

    const int SCAN_BLKS = (N_NODES + 255) / 256;  // 196
    const int EDGE_BLKS = (N_EDGES + 255) / 256;  // 3125

    hipMemsetAsync(deg, 0, (size_t)N_NODES * 4, stream);

    // layer 1 projection
    k_w1<<<(256 * 128 + 255) / 256, 256, 0, stream>>>(Ws, W1);
    k_gemm<256, 128><<<(N_NODES + 63) / 64, 256, 0, stream>>>(x, W1, H1, N_NODES);
    k_s1<<<(N_NODES * 4 + 255) / 256, 256, 0, stream>>>(H1, As, S1o, S1i);

    // CSR build (keyed by src)
    k_count<<<EDGE_BLKS, 256, 0, stream>>>(src, deg);
    k_blocksum<<<SCAN_BLKS, 256, 0, stream>>>(deg, bsum);
    k_scan_bsum<<<1, 256, 0, stream>>>(bsum, boff, SCAN_BLKS);
    k_scan_chunks<<<SCAN_BLKS, 256, 0, stream>>>(deg, boff, row_ptr, cursor);
    k_fill<<<EDGE_BLKS, 256, 0, stream>>>(src, dst, cursor, col);

    // layer 1 attention aggregation -> Hc [N,128]
    k_agg4<<<(N_NODES + 3) / 4, 256, 0, stream>>>(row_ptr, col, S1o, S1i, H1, Hc);

    // layer 2
    k_gemm<128, 32><<<(N_NODES + 63) / 64, 256, 0, stream>>>(Hc, Wo, H2, N_NODES);
    k_s2<<<SCAN_BLKS, 256, 0, stream>>>(H2, Ao, S2o, S2i);
    k_agg1<<<(N_NODES * 32 + 255) / 256, 256, 0, stream>>>(row_ptr, col, S2o, S2i, H2, out);
}